// Round 1
// baseline (102.150 us; speedup 1.0000x reference)
//
#include <hip/hip_runtime.h>

// JSD (beta = 0.5) row-wise loss over log-probabilities.
// loss[row] = sum_v 0.5*p*(lp - log m) + 0.5*q*(lq - log m),  m = 0.5*(p+q)
// N = 2048 rows, V = 32000 vocab. Memory-bound: 524 MB read -> ~83us floor.

#define JSD_V 32000
#define JSD_V4 (JSD_V / 4)
#define JSD_BETA 0.5f

__global__ __launch_bounds__(256) void jsd_kernel(
    const float* __restrict__ log_q,
    const float* __restrict__ log_p,
    float* __restrict__ out)
{
    const int row = blockIdx.x;
    const float4* __restrict__ lq4 = reinterpret_cast<const float4*>(log_q + (size_t)row * JSD_V);
    const float4* __restrict__ lp4 = reinterpret_cast<const float4*>(log_p + (size_t)row * JSD_V);

    float acc = 0.0f;
    for (int i = threadIdx.x; i < JSD_V4; i += 256) {
        float4 a = lq4[i];
        float4 b = lp4[i];
        const float* av = &a.x;
        const float* bv = &b.x;
#pragma unroll
        for (int j = 0; j < 4; ++j) {
            float lq = av[j];
            float lp = bv[j];
            float p = expf(lp);
            float q = expf(lq);
            float m = 0.5f * (p + q);        // lerp(q, p, 0.5)
            float logm = logf(m);
            // beta*KL(P||M) + (1-beta)*KL(Q||M) contribution
            acc += JSD_BETA * (p * (lp - logm)) + (1.0f - JSD_BETA) * (q * (lq - logm));
        }
    }

    // wave (64-lane) reduction
#pragma unroll
    for (int off = 32; off > 0; off >>= 1)
        acc += __shfl_down(acc, off, 64);

    __shared__ float smem[4];
    const int lane = threadIdx.x & 63;
    const int wave = threadIdx.x >> 6;
    if (lane == 0) smem[wave] = acc;
    __syncthreads();
    if (threadIdx.x == 0)
        out[row] = smem[0] + smem[1] + smem[2] + smem[3];
}

extern "C" void kernel_launch(void* const* d_in, const int* in_sizes, int n_in,
                              void* d_out, int out_size, void* d_ws, size_t ws_size,
                              hipStream_t stream) {
    const float* log_q = (const float*)d_in[0];
    const float* log_p = (const float*)d_in[1];
    float* out = (float*)d_out;
    const int n_rows = out_size;  // 2048
    jsd_kernel<<<n_rows, 256, 0, stream>>>(log_q, log_p, out);
}

// Round 2
// 97.049 us; speedup vs baseline: 1.0526x; 1.0526x over previous
//
#include <hip/hip_runtime.h>

// JSD (beta = 0.5) row-wise loss over log-probabilities.
// loss[row] = sum_v [ 0.5*p*(lp - log m) + 0.5*q*(lq - log m) ],  m = 0.5*(p+q)
//           = sum_v [ 0.5*(p*lp + q*lq) - m*log(m) ]
// Base-2 form (a = lp*log2e, b = lq*log2e, p = 2^a, q = 2^b):
//           = ln2 * sum_v [ 0.5*(p*a + q*b) - m*log2(m) ]
// N = 2048 rows, V = 32000. R1 showed ~78us of absolute VALU-issue time from
// precise ocml expf/logf -> use native v_exp_f32 / v_log_f32 (safe: inputs in
// [-36,0], m in (5e-14,1], no denormal/NaN paths).

#define JSD_V 32000
#define JSD_V4 (JSD_V / 4)

__global__ __launch_bounds__(256) void jsd_kernel(
    const float* __restrict__ log_q,
    const float* __restrict__ log_p,
    float* __restrict__ out)
{
    const int row = blockIdx.x;
    const float4* __restrict__ lq4 = reinterpret_cast<const float4*>(log_q + (size_t)row * JSD_V);
    const float4* __restrict__ lp4 = reinterpret_cast<const float4*>(log_p + (size_t)row * JSD_V);

    const float LOG2E = 1.4426950408889634f;  // 1/ln2

    float acc = 0.0f;
    for (int i = threadIdx.x; i < JSD_V4; i += 256) {
        float4 va = lq4[i];
        float4 vb = lp4[i];
        const float* av = &va.x;
        const float* bv = &vb.x;
#pragma unroll
        for (int j = 0; j < 4; ++j) {
            float b = av[j] * LOG2E;              // log2(q)
            float a = bv[j] * LOG2E;              // log2(p)
            float p = __builtin_amdgcn_exp2f(a);  // v_exp_f32
            float q = __builtin_amdgcn_exp2f(b);
            float t = fmaf(q, b, p * a);          // p*log2(p) + q*log2(q)
            float m = 0.5f * (p + q);
            float lg = __builtin_amdgcn_logf(m);  // v_log_f32 = log2(m)
            acc += fmaf(-m, lg, 0.5f * t);        // 0.5*t - m*log2(m)
        }
    }

    // wave (64-lane) reduction
#pragma unroll
    for (int off = 32; off > 0; off >>= 1)
        acc += __shfl_down(acc, off, 64);

    __shared__ float smem[4];
    const int lane = threadIdx.x & 63;
    const int wave = threadIdx.x >> 6;
    if (lane == 0) smem[wave] = acc;
    __syncthreads();
    if (threadIdx.x == 0) {
        const float LN2 = 0.6931471805599453f;
        out[row] = (smem[0] + smem[1] + smem[2] + smem[3]) * LN2;
    }
}

extern "C" void kernel_launch(void* const* d_in, const int* in_sizes, int n_in,
                              void* d_out, int out_size, void* d_ws, size_t ws_size,
                              hipStream_t stream) {
    const float* log_q = (const float*)d_in[0];
    const float* log_p = (const float*)d_in[1];
    float* out = (float*)d_out;
    const int n_rows = out_size;  // 2048
    jsd_kernel<<<n_rows, 256, 0, stream>>>(log_q, log_p, out);
}

// Round 3
// 94.275 us; speedup vs baseline: 1.0835x; 1.0294x over previous
//
#include <hip/hip_runtime.h>

// JSD (beta = 0.5) row-wise loss over log-probabilities.
// loss[row] = ln2 * sum_v [ 0.5*(p*a + q*b) - m*log2(m) ],
//   a = lp*log2e, b = lq*log2e, p = 2^a, q = 2^b, m = 0.5*(p+q)
// N = 2048 rows, V = 32000. Memory-bound: 524 MB mandatory read, floor ~83us.
// R2: 97us = 5.4 TB/s effective. This round: 2x unroll, dual accumulators
// (4 KB/wave in flight) to test whether MLP/dep-chain slack costs the last 14us.

#define JSD_V4 8000  // 32000 floats / 4 per row

__device__ __forceinline__ float jsd_elem4(float4 va, float4 vb) {
    const float LOG2E = 1.4426950408889634f;
    float r = 0.0f;
    const float* av = &va.x;
    const float* bv = &vb.x;
#pragma unroll
    for (int j = 0; j < 4; ++j) {
        float b = av[j] * LOG2E;              // log2(q)
        float a = bv[j] * LOG2E;              // log2(p)
        float p = __builtin_amdgcn_exp2f(a);
        float q = __builtin_amdgcn_exp2f(b);
        float t = fmaf(q, b, p * a);          // p*log2 p + q*log2 q
        float m = 0.5f * (p + q);
        float lg = __builtin_amdgcn_logf(m);  // log2(m)
        r += fmaf(-m, lg, 0.5f * t);
    }
    return r;
}

__global__ __launch_bounds__(256) void jsd_kernel(
    const float* __restrict__ log_q,
    const float* __restrict__ log_p,
    float* __restrict__ out)
{
    const int row = blockIdx.x;
    const float4* __restrict__ lq4 = reinterpret_cast<const float4*>(log_q + (size_t)row * 32000);
    const float4* __restrict__ lp4 = reinterpret_cast<const float4*>(log_p + (size_t)row * 32000);

    float acc0 = 0.0f, acc1 = 0.0f;
    int i = threadIdx.x;
    // paired iterations: 4 x 1KB wave-loads in flight, independent acc chains
    for (; i + 256 < JSD_V4; i += 512) {
        float4 a0 = lq4[i];
        float4 b0 = lp4[i];
        float4 a1 = lq4[i + 256];
        float4 b1 = lp4[i + 256];
        acc0 += jsd_elem4(a0, b0);
        acc1 += jsd_elem4(a1, b1);
    }
    for (; i < JSD_V4; i += 256)
        acc0 += jsd_elem4(lq4[i], lp4[i]);

    float acc = acc0 + acc1;
    // wave (64-lane) reduction
#pragma unroll
    for (int off = 32; off > 0; off >>= 1)
        acc += __shfl_down(acc, off, 64);

    __shared__ float smem[4];
    const int lane = threadIdx.x & 63;
    const int wave = threadIdx.x >> 6;
    if (lane == 0) smem[wave] = acc;
    __syncthreads();
    if (threadIdx.x == 0) {
        const float LN2 = 0.6931471805599453f;
        out[row] = (smem[0] + smem[1] + smem[2] + smem[3]) * LN2;
    }
}

extern "C" void kernel_launch(void* const* d_in, const int* in_sizes, int n_in,
                              void* d_out, int out_size, void* d_ws, size_t ws_size,
                              hipStream_t stream) {
    const float* log_q = (const float*)d_in[0];
    const float* log_p = (const float*)d_in[1];
    float* out = (float*)d_out;
    jsd_kernel<<<out_size, 256, 0, stream>>>(log_q, log_p, out);
}

// Round 4
// 92.730 us; speedup vs baseline: 1.1016x; 1.0167x over previous
//
#include <hip/hip_runtime.h>

// JSD (beta = 0.5) row-wise loss over log-probabilities.
// loss[row] = ln2 * sum_v [ 0.5*(p*a + q*b) - m*log2(m) ],
//   a = lp*log2e, b = lq*log2e, p = 2^a, q = 2^b, m = 0.5*(p+q)
// N = 2048 rows, V = 32000. Memory-bound: 524 MB logical read (262 MB HBM +
// 262 MB L3 at capacity). R3: 94.3us = 5.56 TB/s effective vs 6.86 TB/s fill
// ceiling. This round: 4x unroll, 4 acc chains, 8 KB/wave in flight.

#define JSD_V4 8000  // 32000 floats / 4 per row

__device__ __forceinline__ float jsd_elem4(float4 va, float4 vb) {
    const float LOG2E = 1.4426950408889634f;
    float r = 0.0f;
    const float* av = &va.x;
    const float* bv = &vb.x;
#pragma unroll
    for (int j = 0; j < 4; ++j) {
        float b = av[j] * LOG2E;              // log2(q)
        float a = bv[j] * LOG2E;              // log2(p)
        float p = __builtin_amdgcn_exp2f(a);
        float q = __builtin_amdgcn_exp2f(b);
        float t = fmaf(q, b, p * a);          // p*log2 p + q*log2 q
        float m = 0.5f * (p + q);
        float lg = __builtin_amdgcn_logf(m);  // log2(m)
        r += fmaf(-m, lg, 0.5f * t);
    }
    return r;
}

__global__ __launch_bounds__(256) void jsd_kernel(
    const float* __restrict__ log_q,
    const float* __restrict__ log_p,
    float* __restrict__ out)
{
    const int tid = threadIdx.x;
    const int row = blockIdx.x;
    const float4* __restrict__ lq4 = reinterpret_cast<const float4*>(log_q + (size_t)row * 32000);
    const float4* __restrict__ lp4 = reinterpret_cast<const float4*>(log_p + (size_t)row * 32000);

    float acc0 = 0.0f, acc1 = 0.0f, acc2 = 0.0f, acc3 = 0.0f;

    // Uniform main loop: 7 iterations x unroll-4 covers strides s=0..27
    // (indices tid + 256*s, max 255 + 27*256 = 7167 < 8000).
    int i = tid;
#pragma unroll 1
    for (int k = 0; k < 7; ++k, i += 1024) {
        float4 a0 = lq4[i];
        float4 b0 = lp4[i];
        float4 a1 = lq4[i + 256];
        float4 b1 = lp4[i + 256];
        float4 a2 = lq4[i + 512];
        float4 b2 = lp4[i + 512];
        float4 a3 = lq4[i + 768];
        float4 b3 = lp4[i + 768];
        acc0 += jsd_elem4(a0, b0);
        acc1 += jsd_elem4(a1, b1);
        acc2 += jsd_elem4(a2, b2);
        acc3 += jsd_elem4(a3, b3);
    }
    // Tail: s = 28,29,30 uniform (i = tid + 7168; max 255+7680 = 7935 < 8000)
    {
        float4 a0 = lq4[i];
        float4 b0 = lp4[i];
        float4 a1 = lq4[i + 256];
        float4 b1 = lp4[i + 256];
        float4 a2 = lq4[i + 512];
        float4 b2 = lp4[i + 512];
        acc0 += jsd_elem4(a0, b0);
        acc1 += jsd_elem4(a1, b1);
        acc2 += jsd_elem4(a2, b2);
    }
    // s = 31: only tid < 64 (7936 + tid < 8000)
    if (tid < 64)
        acc3 += jsd_elem4(lq4[i + 768], lp4[i + 768]);

    float acc = (acc0 + acc1) + (acc2 + acc3);
    // wave (64-lane) reduction
#pragma unroll
    for (int off = 32; off > 0; off >>= 1)
        acc += __shfl_down(acc, off, 64);

    __shared__ float smem[4];
    const int lane = tid & 63;
    const int wave = tid >> 6;
    if (lane == 0) smem[wave] = acc;
    __syncthreads();
    if (tid == 0) {
        const float LN2 = 0.6931471805599453f;
        out[row] = (smem[0] + smem[1] + smem[2] + smem[3]) * LN2;
    }
}

extern "C" void kernel_launch(void* const* d_in, const int* in_sizes, int n_in,
                              void* d_out, int out_size, void* d_ws, size_t ws_size,
                              hipStream_t stream) {
    const float* log_q = (const float*)d_in[0];
    const float* log_p = (const float*)d_in[1];
    float* out = (float*)d_out;
    jsd_kernel<<<out_size, 256, 0, stream>>>(log_q, log_p, out);
}

// Round 6
// 80.717 us; speedup vs baseline: 1.2655x; 1.1488x over previous
//
#include <hip/hip_runtime.h>

// JSD (beta = 0.5) row-wise loss over log-probabilities.
// loss[row] = ln2 * sum_v [ 0.5*(p*a + q*b) - m*log2(m) ],
//   a = lp*log2e, b = lq*log2e, p = 2^a, q = 2^b, m = 0.5*(p+q)
// N = 2048 rows, V = 32000. Memory-bound: 524 MB mandatory read.
// R4: 92.7us = 5.66 TB/s. MLP saturated; FETCH=262MB = structural max L3 hit.
// R5 fix: __builtin_nontemporal_load needs a NATIVE vector type, not
// HIP_vector_type<float,4> -> use ext_vector_type(4) float.

#define JSD_V4 8000  // 32000 floats / 4 per row

typedef float v4f __attribute__((ext_vector_type(4)));

__device__ __forceinline__ v4f ntload4(const v4f* p) {
    return __builtin_nontemporal_load(p);
}

__device__ __forceinline__ float jsd_elem4(v4f va, v4f vb) {
    const float LOG2E = 1.4426950408889634f;
    float r = 0.0f;
#pragma unroll
    for (int j = 0; j < 4; ++j) {
        float b = va[j] * LOG2E;              // log2(q)
        float a = vb[j] * LOG2E;              // log2(p)
        float p = __builtin_amdgcn_exp2f(a);
        float q = __builtin_amdgcn_exp2f(b);
        float t = fmaf(q, b, p * a);          // p*log2 p + q*log2 q
        float m = 0.5f * (p + q);
        float lg = __builtin_amdgcn_logf(m);  // log2(m)
        r += fmaf(-m, lg, 0.5f * t);
    }
    return r;
}

__global__ __launch_bounds__(256) void jsd_kernel(
    const float* __restrict__ log_q,
    const float* __restrict__ log_p,
    float* __restrict__ out)
{
    const int tid = threadIdx.x;
    const int row = blockIdx.x;
    const v4f* __restrict__ lq4 = reinterpret_cast<const v4f*>(log_q + (size_t)row * 32000);
    const v4f* __restrict__ lp4 = reinterpret_cast<const v4f*>(log_p + (size_t)row * 32000);

    float acc0 = 0.0f, acc1 = 0.0f, acc2 = 0.0f, acc3 = 0.0f;

    // Uniform main loop: 7 iterations x unroll-4 covers strides s=0..27
    // (indices tid + 256*s, max 255 + 27*256 = 7167 < 8000).
    int i = tid;
#pragma unroll 1
    for (int k = 0; k < 7; ++k, i += 1024) {
        v4f a0 = ntload4(&lq4[i]);
        v4f b0 = ntload4(&lp4[i]);
        v4f a1 = ntload4(&lq4[i + 256]);
        v4f b1 = ntload4(&lp4[i + 256]);
        v4f a2 = ntload4(&lq4[i + 512]);
        v4f b2 = ntload4(&lp4[i + 512]);
        v4f a3 = ntload4(&lq4[i + 768]);
        v4f b3 = ntload4(&lp4[i + 768]);
        acc0 += jsd_elem4(a0, b0);
        acc1 += jsd_elem4(a1, b1);
        acc2 += jsd_elem4(a2, b2);
        acc3 += jsd_elem4(a3, b3);
    }
    // Tail: s = 28,29,30 uniform (i = tid + 7168; max 255+7680 = 7935 < 8000)
    {
        v4f a0 = ntload4(&lq4[i]);
        v4f b0 = ntload4(&lp4[i]);
        v4f a1 = ntload4(&lq4[i + 256]);
        v4f b1 = ntload4(&lp4[i + 256]);
        v4f a2 = ntload4(&lq4[i + 512]);
        v4f b2 = ntload4(&lp4[i + 512]);
        acc0 += jsd_elem4(a0, b0);
        acc1 += jsd_elem4(a1, b1);
        acc2 += jsd_elem4(a2, b2);
    }
    // s = 31: only tid < 64 (7936 + tid < 8000)
    if (tid < 64)
        acc3 += jsd_elem4(ntload4(&lq4[i + 768]), ntload4(&lp4[i + 768]));

    float acc = (acc0 + acc1) + (acc2 + acc3);
    // wave (64-lane) reduction
#pragma unroll
    for (int off = 32; off > 0; off >>= 1)
        acc += __shfl_down(acc, off, 64);

    __shared__ float smem[4];
    const int lane = tid & 63;
    const int wave = tid >> 6;
    if (lane == 0) smem[wave] = acc;
    __syncthreads();
    if (tid == 0) {
        const float LN2 = 0.6931471805599453f;
        out[row] = (smem[0] + smem[1] + smem[2] + smem[3]) * LN2;
    }
}

extern "C" void kernel_launch(void* const* d_in, const int* in_sizes, int n_in,
                              void* d_out, int out_size, void* d_ws, size_t ws_size,
                              hipStream_t stream) {
    const float* log_q = (const float*)d_in[0];
    const float* log_p = (const float*)d_in[1];
    float* out = (float*)d_out;
    jsd_kernel<<<out_size, 256, 0, stream>>>(log_q, log_p, out);
}